// Round 4
// baseline (402.273 us; speedup 1.0000x reference)
//
#include <hip/hip_runtime.h>

// CRF NLL forward (log-partition) + gold score.
// R7: 4-wave cooperative matvec (R6 structure) + non-draining barrier.
// Exp-space recursion E_{s+1} = exp(feats_s) * (W @ E_s), W = exp(transitions),
// exact power-of-2 renormalization every 4 steps (integer log2 offset C).
//
// Key change vs R6: the per-step __syncthreads() compiled to
// "s_waitcnt vmcnt(0) lgkmcnt(0); s_barrier", draining the feats prefetch
// queue every step -> each step serialized on an L2/L3 load (~200-600 cyc),
// which matched the measured 565 cyc/step. The in-loop barrier is now raw
//   s_waitcnt lgkmcnt(0); s_barrier
// (LDS ordering only; global prefetch loads stay in flight across steps,
// consumed via compiler-counted vmcnt(N) at the top of each step).

#define TT 64

// LDS-ordering barrier that does NOT drain vmcnt (prefetch stays in flight).
#define BAR() asm volatile("s_waitcnt lgkmcnt(0)\n\ts_barrier" ::: "memory")

__global__ __launch_bounds__(256, 2) void crf_fwd_kernel(
    const float* __restrict__ feats, const int* __restrict__ tags,
    const int* __restrict__ lengths, const float* __restrict__ trans,
    const int* __restrict__ p_start, const int* __restrict__ p_stop,
    float* __restrict__ out, int B, int S) {
  const int tid = threadIdx.x;
  const int lane = tid & 63;
  const int w = tid >> 6;        // wave 0..3
  const int cg = lane >> 4;      // column group 0..3
  const int li = lane & 15;
  const int r = w * 16 + li;     // output row this lane computes
  const int b = blockIdx.x;

  __shared__ float s_trans[TT * TT];
  __shared__ __align__(16) float s_E[2][TT];
  __shared__ float s_part[4];

  for (int i = tid * 4; i < TT * TT; i += 256 * 4) {
    *reinterpret_cast<float4*>(&s_trans[i]) =
        *reinterpret_cast<const float4*>(trans + i);
  }
  __syncthreads();

  const int start = *p_start;
  const int stop = *p_stop;
  const int len = lengths[b];

  // W slice: q_j = exp(trans[r][cg*16+j]), j=0..15 (one-time strided LDS read)
  float q0, q1, q2, q3, q4, q5, q6, q7, q8, q9, q10, q11, q12, q13, q14, q15;
  {
    const float* wr = s_trans + r * TT + cg * 16;
    float4 t0 = *reinterpret_cast<const float4*>(wr + 0);
    float4 t1 = *reinterpret_cast<const float4*>(wr + 4);
    float4 t2 = *reinterpret_cast<const float4*>(wr + 8);
    float4 t3 = *reinterpret_cast<const float4*>(wr + 12);
    q0 = __expf(t0.x); q1 = __expf(t0.y); q2 = __expf(t0.z); q3 = __expf(t0.w);
    q4 = __expf(t1.x); q5 = __expf(t1.y); q6 = __expf(t1.z); q7 = __expf(t1.w);
    q8 = __expf(t2.x); q9 = __expf(t2.y); q10 = __expf(t2.z); q11 = __expf(t2.w);
    q12 = __expf(t3.x); q13 = __expf(t3.y); q14 = __expf(t3.z); q15 = __expf(t3.w);
  }
  float ws_e = __expf(s_trans[stop * TT + lane]);  // for final reduce

  const float* fbase = feats + (size_t)b * S * TT;
  const float* fbr = fbase + r;  // this lane's row element, stride TT per step
  const int* tb = tags + (size_t)b * S;

  // init: E_1[t] = exp(feats[0,t]) * exp(trans[t][start])
  // (all other init contributions are exp(-1e4) == 0 exactly in fp32)
  {
    float iv = __expf(fbase[r]) * __expf(s_trans[r * TT + start]);
    if (cg == 0) s_E[0][r] = iv;
  }
  int C = 0;
  int buf = 0;
  __syncthreads();

  // prefetch ring: e_j = expf(row 1+j) ready; f_j = row 9+j in flight
#define PRIME(J)                                                               \
  float e##J = __expf(fbr[(size_t)TT * ((1 + (J)) < S ? (1 + (J)) : S - 1)]);  \
  float f##J = fbr[(size_t)TT * ((9 + (J)) < S ? (9 + (J)) : S - 1)];
  PRIME(0) PRIME(1) PRIME(2) PRIME(3)
  PRIME(4) PRIME(5) PRIME(6) PRIME(7)
#undef PRIME

  // 16-FMA cooperative matvec of the lane's (row, col-group) slice
#define MATVEC16(SUM, XB)                                                      \
  float4 x0 = *reinterpret_cast<const float4*>((XB) + cg * 16 + 0);            \
  float4 x1 = *reinterpret_cast<const float4*>((XB) + cg * 16 + 4);            \
  float4 x2 = *reinterpret_cast<const float4*>((XB) + cg * 16 + 8);            \
  float4 x3 = *reinterpret_cast<const float4*>((XB) + cg * 16 + 12);           \
  float a0 = q0 * x0.x; float a1 = q1 * x0.y;                                  \
  float a2 = q2 * x0.z; float a3 = q3 * x0.w;                                  \
  a0 = fmaf(q4, x1.x, a0); a1 = fmaf(q5, x1.y, a1);                            \
  a2 = fmaf(q6, x1.z, a2); a3 = fmaf(q7, x1.w, a3);                            \
  a0 = fmaf(q8, x2.x, a0); a1 = fmaf(q9, x2.y, a1);                            \
  a2 = fmaf(q10, x2.z, a2); a3 = fmaf(q11, x2.w, a3);                          \
  a0 = fmaf(q12, x3.x, a0); a1 = fmaf(q13, x3.y, a1);                          \
  a2 = fmaf(q14, x3.z, a2); a3 = fmaf(q15, x3.w, a3);                          \
  float SUM = (a0 + a1) + (a2 + a3);                                           \
  SUM += __shfl_xor(SUM, 16, 64);                                              \
  SUM += __shfl_xor(SUM, 32, 64);

  // step: consume ring slot J, advance E (LDS buf -> buf^1), refill ring.
  // Order: vmcnt-counted consume of f##J FIRST (overlaps ds_read latency),
  // then refill load issue, then matvec. RN=1: renorm via exponent of E[3]
  // of the buffer being consumed.
#define STEP(J, SBASE, RN)                                                     \
  {                                                                            \
    float ecur = e##J;                                                         \
    e##J = __expf(f##J);                                                       \
    int pidx = (SBASE) + (J) + 16;                                             \
    pidx = pidx < S ? pidx : S - 1;                                             \
    f##J = fbr[(size_t)TT * pidx];                                             \
    const float* Eb = s_E[buf];                                                \
    MATVEC16(sum, Eb);                                                         \
    float En;                                                                  \
    if (RN) {                                                                  \
      unsigned rb = __builtin_bit_cast(unsigned, Eb[3]);                       \
      int k = (int)((rb >> 23) & 0xFFu) - 127;                                 \
      C += k;                                                                  \
      float sc = __builtin_bit_cast(float, (unsigned)(127 - k) << 23);         \
      En = ecur * sum * sc;                                                    \
    } else {                                                                   \
      En = ecur * sum;                                                         \
    }                                                                          \
    if (cg == 0) s_E[buf ^ 1][r] = En;                                         \
    buf ^= 1;                                                                  \
    BAR();                                                                     \
  }

  int s = 1;
#pragma unroll 1
  for (; s + 8 <= len; s += 8) {
    STEP(0, s, 0) STEP(1, s, 0) STEP(2, s, 0) STEP(3, s, 1)
    STEP(4, s, 0) STEP(5, s, 0) STEP(6, s, 0) STEP(7, s, 1)
  }
#pragma unroll 1
  for (; s < len; ++s) {  // tail <8 iters: rows L1-hot; renorm every step
    const float* Eb = s_E[buf];
    MATVEC16(sum, Eb);
    unsigned rb = __builtin_bit_cast(unsigned, Eb[3]);
    int k = (int)((rb >> 23) & 0xFFu) - 127;
    C += k;
    float sc = __builtin_bit_cast(float, (unsigned)(127 - k) << 23);
    float ecur = __expf(fbr[(size_t)TT * s]);
    float En = ecur * sum * sc;
    if (cg == 0) s_E[buf ^ 1][r] = En;
    buf ^= 1;
    BAR();
  }

  // alpha = C*ln2 + log(sum_t E[t] * exp(trans[stop, t]))  (computed by all)
  float v = s_E[buf][lane] * ws_e;
#pragma unroll
  for (int off = 32; off >= 1; off >>= 1) v += __shfl_xor(v, off, 64);
  float alpha = __logf(v) + (float)C * 0.6931471805599453f;

  // gold path score, block-parallel over steps:
  // thread j handles steps j, j+256, ...
  float gs = 0.0f;
#pragma unroll 1
  for (int s0 = 0; s0 < len; s0 += 256) {
    int si = s0 + tid;
    if (si < len) {
      int t = tb[si];
      int tp = (si == 0) ? start : tb[si - 1];
      gs += s_trans[t * TT + tp] + fbase[(size_t)si * TT + t];
    }
  }
#pragma unroll
  for (int off = 32; off >= 1; off >>= 1) gs += __shfl_xor(gs, off, 64);
  if (lane == 0) s_part[w] = gs;
  __syncthreads();
  if (tid == 0) {
    float gold = (s_part[0] + s_part[1]) + (s_part[2] + s_part[3]) +
                 s_trans[stop * TT + tb[len - 1]];
    out[b] = alpha - gold;
  }
}

extern "C" void kernel_launch(void* const* d_in, const int* in_sizes, int n_in,
                              void* d_out, int out_size, void* d_ws, size_t ws_size,
                              hipStream_t stream) {
  const float* feats = (const float*)d_in[0];
  const int* tags = (const int*)d_in[1];
  const int* lengths = (const int*)d_in[2];
  // d_in[3] = masks: unused; masks[b,s] == (s < lengths[b]) by construction
  const float* trans = (const float*)d_in[4];
  const int* p_start = (const int*)d_in[5];
  const int* p_stop = (const int*)d_in[6];
  float* out = (float*)d_out;

  int B = in_sizes[2];
  int S = in_sizes[1] / B;
  crf_fwd_kernel<<<B, 256, 0, stream>>>(feats, tags, lengths, trans,
                                        p_start, p_stop, out, B, S);
}

// Round 6
// 377.437 us; speedup vs baseline: 1.0658x; 1.0658x over previous
//
#include <hip/hip_runtime.h>

// CRF NLL forward (log-partition) + gold score.
// R9: 2-wave cooperative matvec, VALU cross-half reduce via the
// __builtin_amdgcn_permlane32_swap intrinsic (R8's raw inline-asm version
// failed correctness -- suspected tied-operand misallocation; the builtin
// has compiler-modeled semantics). Renorm key reverted to the R6-proven
// uniform LDS read of Eb[3].
//
// Exp-space recursion E_{s+1} = exp(feats_s) * (W @ E_s), W = exp(transitions),
// exact power-of-2 renormalization every 4 steps (integer log2 offset C).
//
// Layout: wave w, lane l -> row r = w*32 + (l&31), col-half cg = l>>5.
// Each lane: 32 FMAs over columns cg*32..cg*32+31 (W slice in 32 VGPRs).
// Cross-half reduce: permlane32_swap(s, s) -> halves exchanged across the
// lane<32 / lane>=32 boundary; sum of both results = s[l] + s[l^32] in every
// lane under any swap direction (direction-proof because both inputs are s).
// This replaces the two serial ds_bpermute shuffles (~200 cyc) of R6/R7.

#define TT 64

__device__ __forceinline__ float xhalf_sum(float s) {
  unsigned u = __builtin_bit_cast(unsigned, s);
  auto p = __builtin_amdgcn_permlane32_swap(u, u, false, false);
  return __builtin_bit_cast(float, (unsigned)p[0]) +
         __builtin_bit_cast(float, (unsigned)p[1]);
}

__global__ __launch_bounds__(128, 1) void crf_fwd_kernel(
    const float* __restrict__ feats, const int* __restrict__ tags,
    const int* __restrict__ lengths, const float* __restrict__ trans,
    const int* __restrict__ p_start, const int* __restrict__ p_stop,
    float* __restrict__ out, int B, int S) {
  const int tid = threadIdx.x;
  const int lane = tid & 63;
  const int w = tid >> 6;        // wave 0..1
  const int cg = lane >> 5;      // column half 0..1
  const int li = lane & 31;
  const int r = w * 32 + li;     // output row this lane computes
  const int b = blockIdx.x;

  __shared__ float s_trans[TT * TT];
  __shared__ __align__(16) float s_E[2][TT];
  __shared__ float s_part[2];

  for (int i = tid * 4; i < TT * TT; i += 128 * 4) {
    *reinterpret_cast<float4*>(&s_trans[i]) =
        *reinterpret_cast<const float4*>(trans + i);
  }
  __syncthreads();

  const int start = *p_start;
  const int stop = *p_stop;
  const int len = lengths[b];

  // W slice: q_j = exp(trans[r][cg*32+j]), j=0..31 (one-time strided LDS read)
  float q0, q1, q2, q3, q4, q5, q6, q7, q8, q9, q10, q11, q12, q13, q14, q15,
      q16, q17, q18, q19, q20, q21, q22, q23, q24, q25, q26, q27, q28, q29,
      q30, q31;
  {
    const float* wr = s_trans + r * TT + (cg << 5);
    float4 t;
    t = *reinterpret_cast<const float4*>(wr + 0);
    q0 = __expf(t.x); q1 = __expf(t.y); q2 = __expf(t.z); q3 = __expf(t.w);
    t = *reinterpret_cast<const float4*>(wr + 4);
    q4 = __expf(t.x); q5 = __expf(t.y); q6 = __expf(t.z); q7 = __expf(t.w);
    t = *reinterpret_cast<const float4*>(wr + 8);
    q8 = __expf(t.x); q9 = __expf(t.y); q10 = __expf(t.z); q11 = __expf(t.w);
    t = *reinterpret_cast<const float4*>(wr + 12);
    q12 = __expf(t.x); q13 = __expf(t.y); q14 = __expf(t.z); q15 = __expf(t.w);
    t = *reinterpret_cast<const float4*>(wr + 16);
    q16 = __expf(t.x); q17 = __expf(t.y); q18 = __expf(t.z); q19 = __expf(t.w);
    t = *reinterpret_cast<const float4*>(wr + 20);
    q20 = __expf(t.x); q21 = __expf(t.y); q22 = __expf(t.z); q23 = __expf(t.w);
    t = *reinterpret_cast<const float4*>(wr + 24);
    q24 = __expf(t.x); q25 = __expf(t.y); q26 = __expf(t.z); q27 = __expf(t.w);
    t = *reinterpret_cast<const float4*>(wr + 28);
    q28 = __expf(t.x); q29 = __expf(t.y); q30 = __expf(t.z); q31 = __expf(t.w);
  }
  float ws_e = __expf(s_trans[stop * TT + lane]);  // for final reduce

  const float* fbase = feats + (size_t)b * S * TT;
  const float* fbr = fbase + r;  // this lane's row element, stride TT per step
  const int* tb = tags + (size_t)b * S;

  // init: E_1[t] = exp(feats[0,t]) * exp(trans[t][start])
  // (all other init contributions are exp(-1e4) == 0 exactly in fp32)
  {
    float iv = __expf(fbase[r]) * __expf(s_trans[r * TT + start]);
    if (cg == 0) s_E[0][r] = iv;
  }
  int C = 0;
  int buf = 0;
  __syncthreads();

  // prefetch ring: e_j = expf(row 1+j) ready; f_j = row 9+j in flight
#define PRIME(J)                                                               \
  float e##J = __expf(fbr[(size_t)TT * ((1 + (J)) < S ? (1 + (J)) : S - 1)]);  \
  float f##J = fbr[(size_t)TT * ((9 + (J)) < S ? (9 + (J)) : S - 1)];
  PRIME(0) PRIME(1) PRIME(2) PRIME(3)
  PRIME(4) PRIME(5) PRIME(6) PRIME(7)
#undef PRIME

  // 32-FMA matvec of the lane's (row, col-half) slice + VALU cross-half sum.
#define MATVEC32(SUM, XB)                                                      \
  const float* xb = (XB) + (cg << 5);                                          \
  float4 x0 = *reinterpret_cast<const float4*>(xb + 0);                        \
  float4 x1 = *reinterpret_cast<const float4*>(xb + 4);                        \
  float4 x2 = *reinterpret_cast<const float4*>(xb + 8);                        \
  float4 x3 = *reinterpret_cast<const float4*>(xb + 12);                       \
  float4 x4 = *reinterpret_cast<const float4*>(xb + 16);                       \
  float4 x5 = *reinterpret_cast<const float4*>(xb + 20);                       \
  float4 x6 = *reinterpret_cast<const float4*>(xb + 24);                       \
  float4 x7 = *reinterpret_cast<const float4*>(xb + 28);                       \
  float a0 = q0 * x0.x, a1 = q1 * x0.y, a2 = q2 * x0.z, a3 = q3 * x0.w;        \
  a0 = fmaf(q4, x1.x, a0); a1 = fmaf(q5, x1.y, a1);                            \
  a2 = fmaf(q6, x1.z, a2); a3 = fmaf(q7, x1.w, a3);                            \
  a0 = fmaf(q8, x2.x, a0); a1 = fmaf(q9, x2.y, a1);                            \
  a2 = fmaf(q10, x2.z, a2); a3 = fmaf(q11, x2.w, a3);                          \
  a0 = fmaf(q12, x3.x, a0); a1 = fmaf(q13, x3.y, a1);                          \
  a2 = fmaf(q14, x3.z, a2); a3 = fmaf(q15, x3.w, a3);                          \
  a0 = fmaf(q16, x4.x, a0); a1 = fmaf(q17, x4.y, a1);                          \
  a2 = fmaf(q18, x4.z, a2); a3 = fmaf(q19, x4.w, a3);                          \
  a0 = fmaf(q20, x5.x, a0); a1 = fmaf(q21, x5.y, a1);                          \
  a2 = fmaf(q22, x5.z, a2); a3 = fmaf(q23, x5.w, a3);                          \
  a0 = fmaf(q24, x6.x, a0); a1 = fmaf(q25, x6.y, a1);                          \
  a2 = fmaf(q26, x6.z, a2); a3 = fmaf(q27, x6.w, a3);                          \
  a0 = fmaf(q28, x7.x, a0); a1 = fmaf(q29, x7.y, a1);                          \
  a2 = fmaf(q30, x7.z, a2); a3 = fmaf(q31, x7.w, a3);                          \
  float SUM = xhalf_sum((a0 + a1) + (a2 + a3));

  // step: consume ring slot J, advance E (LDS buf -> buf^1), refill ring.
  // RN=1: renorm via exponent of Eb[3] (uniform LDS read, R6-proven).
#define STEP(J, SBASE, RN)                                                     \
  {                                                                            \
    const float* Eb = s_E[buf];                                                \
    MATVEC32(sum, Eb);                                                         \
    float ecur = e##J;                                                         \
    e##J = __expf(f##J);                                                       \
    int pidx = (SBASE) + (J) + 16;                                             \
    pidx = pidx < S ? pidx : S - 1;                                            \
    f##J = fbr[(size_t)TT * pidx];                                             \
    float En;                                                                  \
    if (RN) {                                                                  \
      unsigned rb = __builtin_bit_cast(unsigned, Eb[3]);                       \
      int k = (int)((rb >> 23) & 0xFFu) - 127;                                 \
      C += k;                                                                  \
      float sc = __builtin_bit_cast(float, (unsigned)(127 - k) << 23);         \
      En = ecur * sum * sc;                                                    \
    } else {                                                                   \
      En = ecur * sum;                                                         \
    }                                                                          \
    if (cg == 0) s_E[buf ^ 1][r] = En;                                         \
    buf ^= 1;                                                                  \
    __syncthreads();                                                           \
  }

  int s = 1;
#pragma unroll 1
  for (; s + 8 <= len; s += 8) {
    STEP(0, s, 0) STEP(1, s, 0) STEP(2, s, 0) STEP(3, s, 1)
    STEP(4, s, 0) STEP(5, s, 0) STEP(6, s, 0) STEP(7, s, 1)
  }
#pragma unroll 1
  for (; s < len; ++s) {  // tail <8 iters: rows L1-hot; renorm every step
    const float* Eb = s_E[buf];
    MATVEC32(sum, Eb);
    unsigned rb = __builtin_bit_cast(unsigned, Eb[3]);
    int k = (int)((rb >> 23) & 0xFFu) - 127;
    C += k;
    float sc = __builtin_bit_cast(float, (unsigned)(127 - k) << 23);
    float ecur = __expf(fbr[(size_t)TT * s]);
    float En = ecur * sum * sc;
    if (cg == 0) s_E[buf ^ 1][r] = En;
    buf ^= 1;
    __syncthreads();
  }

  // alpha = C*ln2 + log(sum_t E[t] * exp(trans[stop, t]))  (computed by all)
  float v = s_E[buf][lane] * ws_e;
#pragma unroll
  for (int off = 32; off >= 1; off >>= 1) v += __shfl_xor(v, off, 64);
  float alpha = __logf(v) + (float)C * 0.6931471805599453f;

  // gold path score, block-parallel over steps:
  // thread j handles steps j, j+128, ...
  float gs = 0.0f;
#pragma unroll 1
  for (int s0 = 0; s0 < len; s0 += 128) {
    int si = s0 + tid;
    if (si < len) {
      int t = tb[si];
      int tp = (si == 0) ? start : tb[si - 1];
      gs += s_trans[t * TT + tp] + fbase[(size_t)si * TT + t];
    }
  }
#pragma unroll
  for (int off = 32; off >= 1; off >>= 1) gs += __shfl_xor(gs, off, 64);
  if (lane == 0) s_part[w] = gs;
  __syncthreads();
  if (tid == 0) {
    float gold = s_part[0] + s_part[1] + s_trans[stop * TT + tb[len - 1]];
    out[b] = alpha - gold;
  }
}

extern "C" void kernel_launch(void* const* d_in, const int* in_sizes, int n_in,
                              void* d_out, int out_size, void* d_ws, size_t ws_size,
                              hipStream_t stream) {
  const float* feats = (const float*)d_in[0];
  const int* tags = (const int*)d_in[1];
  const int* lengths = (const int*)d_in[2];
  // d_in[3] = masks: unused; masks[b,s] == (s < lengths[b]) by construction
  const float* trans = (const float*)d_in[4];
  const int* p_start = (const int*)d_in[5];
  const int* p_stop = (const int*)d_in[6];
  float* out = (float*)d_out;

  int B = in_sizes[2];
  int S = in_sizes[1] / B;
  crf_fwd_kernel<<<B, 128, 0, stream>>>(feats, tags, lengths, trans,
                                        p_start, p_stop, out, B, S);
}

// Round 12
// 362.887 us; speedup vs baseline: 1.1085x; 1.0401x over previous
//
#include <hip/hip_runtime.h>

// CRF NLL forward (log-partition) + gold score.
// R13: 4-wave cooperative matvec + all-VALU cross-group reduce.
// Composition of two PROVEN halves: R6's 4-wave layout (16-FMA slices,
// 4x ds_read_b128) + R9's direction-proof permlane-swap reduce (extended
// to lane^16 via permlane16_swap, lane^32 via permlane32_swap).
// R10-R12's single-wave LDS round-trip is abandoned (3x identical absmax
// failure, scheduling-invariant -> structural, cause not observable here).
//
// Exp-space recursion E_{s+1} = exp(feats_s) * (W @ E_s), W = exp(transitions),
// exact power-of-2 renormalization every 4 steps (integer log2 offset C).
//
// Layout: wave w (0..3), lane l -> row r = w*16 + (l&15), col-group cg = l>>4.
// Each lane: 16 FMAs over columns cg*16..cg*16+15 (W slice in 16 VGPRs,
// loaded from GLOBAL -- avoids R9's 545k one-time LDS bank conflicts).
// Reduce across the 4 column groups: sum += swap16(sum); sum += swap32(sum),
// each swap fed the SAME value in both operands -> direction-proof
// (result = s[l] + s[l^16] resp. + s[l^32] in every lane).

#define TT 64

__device__ __forceinline__ float xquad_sum(float s) {
  // lane^16 exchange
#if __has_builtin(__builtin_amdgcn_permlane16_swap)
  unsigned u = __builtin_bit_cast(unsigned, s);
  auto p = __builtin_amdgcn_permlane16_swap(u, u, false, false);
  float t = __builtin_bit_cast(float, (unsigned)p[0]) +
            __builtin_bit_cast(float, (unsigned)p[1]);
#else
  float t = s + __shfl_xor(s, 16, 64);
#endif
  // lane^32 exchange (R9-proven builtin)
  unsigned u2 = __builtin_bit_cast(unsigned, t);
  auto q = __builtin_amdgcn_permlane32_swap(u2, u2, false, false);
  return __builtin_bit_cast(float, (unsigned)q[0]) +
         __builtin_bit_cast(float, (unsigned)q[1]);
}

__global__ __launch_bounds__(256, 1) void crf_fwd_kernel(
    const float* __restrict__ feats, const int* __restrict__ tags,
    const int* __restrict__ lengths, const float* __restrict__ trans,
    const int* __restrict__ p_start, const int* __restrict__ p_stop,
    float* __restrict__ out, int B, int S) {
  const int tid = threadIdx.x;
  const int lane = tid & 63;
  const int w = tid >> 6;        // wave 0..3
  const int cg = lane >> 4;      // column group 0..3
  const int li = lane & 15;
  const int r = w * 16 + li;     // output row this lane computes
  const int b = blockIdx.x;

  __shared__ float s_trans[TT * TT];
  __shared__ __align__(16) float s_E[2][TT];
  __shared__ float s_part[4];

  for (int i = tid * 4; i < TT * TT; i += 256 * 4) {
    *reinterpret_cast<float4*>(&s_trans[i]) =
        *reinterpret_cast<const float4*>(trans + i);
  }
  __syncthreads();

  const int start = *p_start;
  const int stop = *p_stop;
  const int len = lengths[b];

  // W slice from GLOBAL: q_j = exp(trans[r][cg*16+j]), j=0..15 (one-time;
  // L2-hot after the first blocks; avoids the strided-LDS bank conflicts).
  float q0, q1, q2, q3, q4, q5, q6, q7, q8, q9, q10, q11, q12, q13, q14, q15;
  {
    const float* wr = trans + r * TT + (cg << 4);
    float4 t0 = *reinterpret_cast<const float4*>(wr + 0);
    float4 t1 = *reinterpret_cast<const float4*>(wr + 4);
    float4 t2 = *reinterpret_cast<const float4*>(wr + 8);
    float4 t3 = *reinterpret_cast<const float4*>(wr + 12);
    q0 = __expf(t0.x); q1 = __expf(t0.y); q2 = __expf(t0.z); q3 = __expf(t0.w);
    q4 = __expf(t1.x); q5 = __expf(t1.y); q6 = __expf(t1.z); q7 = __expf(t1.w);
    q8 = __expf(t2.x); q9 = __expf(t2.y); q10 = __expf(t2.z); q11 = __expf(t2.w);
    q12 = __expf(t3.x); q13 = __expf(t3.y); q14 = __expf(t3.z); q15 = __expf(t3.w);
  }
  float ws_e = __expf(s_trans[stop * TT + lane]);  // for final reduce

  const float* fbase = feats + (size_t)b * S * TT;
  const float* fbr = fbase + r;  // this lane's row element, stride TT per step
  const int* tb = tags + (size_t)b * S;

  // init: E_1[t] = exp(feats[0,t]) * exp(trans[t][start])
  // (all other init contributions are exp(-1e4) == 0 exactly in fp32)
  {
    float iv = __expf(fbase[r]) * __expf(s_trans[r * TT + start]);
    if (cg == 0) s_E[0][r] = iv;
  }
  int C = 0;
  int buf = 0;
  __syncthreads();

  // prefetch ring: e_j = expf(row 1+j) ready; f_j = row 9+j in flight
#define PRIME(J)                                                               \
  float e##J = __expf(fbr[(size_t)TT * ((1 + (J)) < S ? (1 + (J)) : S - 1)]);  \
  float f##J = fbr[(size_t)TT * ((9 + (J)) < S ? (9 + (J)) : S - 1)];
  PRIME(0) PRIME(1) PRIME(2) PRIME(3)
  PRIME(4) PRIME(5) PRIME(6) PRIME(7)
#undef PRIME

  // 16-FMA matvec of the lane's (row, col-group) slice + VALU reduce.
#define MATVEC16(SUM, XB)                                                      \
  const float* xb = (XB) + (cg << 4);                                          \
  float4 x0 = *reinterpret_cast<const float4*>(xb + 0);                        \
  float4 x1 = *reinterpret_cast<const float4*>(xb + 4);                        \
  float4 x2 = *reinterpret_cast<const float4*>(xb + 8);                        \
  float4 x3 = *reinterpret_cast<const float4*>(xb + 12);                       \
  float a0 = q0 * x0.x, a1 = q1 * x0.y, a2 = q2 * x0.z, a3 = q3 * x0.w;        \
  a0 = fmaf(q4, x1.x, a0); a1 = fmaf(q5, x1.y, a1);                            \
  a2 = fmaf(q6, x1.z, a2); a3 = fmaf(q7, x1.w, a3);                            \
  a0 = fmaf(q8, x2.x, a0); a1 = fmaf(q9, x2.y, a1);                            \
  a2 = fmaf(q10, x2.z, a2); a3 = fmaf(q11, x2.w, a3);                          \
  a0 = fmaf(q12, x3.x, a0); a1 = fmaf(q13, x3.y, a1);                          \
  a2 = fmaf(q14, x3.z, a2); a3 = fmaf(q15, x3.w, a3);                          \
  float SUM = xquad_sum((a0 + a1) + (a2 + a3));

  // step: consume ring slot J, advance E (LDS buf -> buf^1), refill ring.
  // RN=1: renorm via exponent of Eb[3] (uniform LDS read, R6/R9-proven).
#define STEP(J, SBASE, RN)                                                     \
  {                                                                            \
    const float* Eb = s_E[buf];                                                \
    MATVEC16(sum, Eb);                                                         \
    float ecur = e##J;                                                         \
    e##J = __expf(f##J);                                                       \
    int pidx = (SBASE) + (J) + 16;                                             \
    pidx = pidx < S ? pidx : S - 1;                                            \
    f##J = fbr[(size_t)TT * pidx];                                             \
    float En;                                                                  \
    if (RN) {                                                                  \
      unsigned rb = __builtin_bit_cast(unsigned, Eb[3]);                       \
      int k = (int)((rb >> 23) & 0xFFu) - 127;                                 \
      C += k;                                                                  \
      float sc = __builtin_bit_cast(float, (unsigned)(127 - k) << 23);         \
      En = ecur * sum * sc;                                                    \
    } else {                                                                   \
      En = ecur * sum;                                                         \
    }                                                                          \
    if (cg == 0) s_E[buf ^ 1][r] = En;                                         \
    buf ^= 1;                                                                  \
    __syncthreads();                                                           \
  }

  int s = 1;
#pragma unroll 1
  for (; s + 8 <= len; s += 8) {
    STEP(0, s, 0) STEP(1, s, 0) STEP(2, s, 0) STEP(3, s, 1)
    STEP(4, s, 0) STEP(5, s, 0) STEP(6, s, 0) STEP(7, s, 1)
  }
#pragma unroll 1
  for (; s < len; ++s) {  // tail <8 iters: rows L1-hot; renorm every step
    const float* Eb = s_E[buf];
    MATVEC16(sum, Eb);
    unsigned rb = __builtin_bit_cast(unsigned, Eb[3]);
    int k = (int)((rb >> 23) & 0xFFu) - 127;
    C += k;
    float sc = __builtin_bit_cast(float, (unsigned)(127 - k) << 23);
    float ecur = __expf(fbr[(size_t)TT * s]);
    float En = ecur * sum * sc;
    if (cg == 0) s_E[buf ^ 1][r] = En;
    buf ^= 1;
    __syncthreads();
  }

  // alpha = C*ln2 + log(sum_t E[t] * exp(trans[stop, t]))  (computed by all)
  float v = s_E[buf][lane] * ws_e;
#pragma unroll
  for (int off = 32; off >= 1; off >>= 1) v += __shfl_xor(v, off, 64);
  float alpha = __logf(v) + (float)C * 0.6931471805599453f;

  // gold path score, block-parallel over steps:
  // thread j handles steps j, j+256, ...
  float gs = 0.0f;
#pragma unroll 1
  for (int s0 = 0; s0 < len; s0 += 256) {
    int si = s0 + tid;
    if (si < len) {
      int t = tb[si];
      int tp = (si == 0) ? start : tb[si - 1];
      gs += s_trans[t * TT + tp] + fbase[(size_t)si * TT + t];
    }
  }
#pragma unroll
  for (int off = 32; off >= 1; off >>= 1) gs += __shfl_xor(gs, off, 64);
  if (lane == 0) s_part[w] = gs;
  __syncthreads();
  if (tid == 0) {
    float gold = (s_part[0] + s_part[1]) + (s_part[2] + s_part[3]) +
                 s_trans[stop * TT + tb[len - 1]];
    out[b] = alpha - gold;
  }
}

extern "C" void kernel_launch(void* const* d_in, const int* in_sizes, int n_in,
                              void* d_out, int out_size, void* d_ws, size_t ws_size,
                              hipStream_t stream) {
  const float* feats = (const float*)d_in[0];
  const int* tags = (const int*)d_in[1];
  const int* lengths = (const int*)d_in[2];
  // d_in[3] = masks: unused; masks[b,s] == (s < lengths[b]) by construction
  const float* trans = (const float*)d_in[4];
  const int* p_start = (const int*)d_in[5];
  const int* p_stop = (const int*)d_in[6];
  float* out = (float*)d_out;

  int B = in_sizes[2];
  int S = in_sizes[1] / B;
  crf_fwd_kernel<<<B, 256, 0, stream>>>(feats, tags, lengths, trans,
                                        p_start, p_stop, out, B, S);
}